// Round 1
// baseline (455.951 us; speedup 1.0000x reference)
//
#include <hip/hip_runtime.h>

#define N_NODES 100000
#define F_IN 128
#define H 16

// ---------------------------------------------------------------------------
// k1: y1l = x @ W1l, y1r = x @ W1r  (thread per node; W via uniform s_loads)
// ---------------------------------------------------------------------------
__global__ void __launch_bounds__(256) k_lin1(
    const float* __restrict__ x, const float* __restrict__ W1l,
    const float* __restrict__ W1r, float* __restrict__ y1l,
    float* __restrict__ y1r) {
  int n = blockIdx.x * 256 + threadIdx.x;
  if (n >= N_NODES) return;
  const float4* xr = (const float4*)(x + (size_t)n * F_IN);
  float al[H], ar[H];
#pragma unroll
  for (int c = 0; c < H; ++c) { al[c] = 0.f; ar[c] = 0.f; }
  float4 xv = xr[0];
  for (int k4 = 0; k4 < F_IN / 4; ++k4) {
    float4 cur = xv;
    if (k4 + 1 < F_IN / 4) xv = xr[k4 + 1];  // prefetch next 16B
    float xs[4] = {cur.x, cur.y, cur.z, cur.w};
#pragma unroll
    for (int j = 0; j < 4; ++j) {
      int k = k4 * 4 + j;
#pragma unroll
      for (int c = 0; c < H; ++c) {
        al[c] = fmaf(xs[j], W1l[k * H + c], al[c]);
        ar[c] = fmaf(xs[j], W1r[k * H + c], ar[c]);
      }
    }
  }
  float4* ol = (float4*)(y1l + (size_t)n * H);
  float4* orr = (float4*)(y1r + (size_t)n * H);
#pragma unroll
  for (int q = 0; q < 4; ++q) {
    ol[q] = make_float4(al[4 * q], al[4 * q + 1], al[4 * q + 2], al[4 * q + 3]);
    orr[q] = make_float4(ar[4 * q], ar[4 * q + 1], ar[4 * q + 2], ar[4 * q + 3]);
  }
}

// ---------------------------------------------------------------------------
// scatter: 16 lanes per edge; agg[dst][c] += val[src][c]; optional degree cnt
// ---------------------------------------------------------------------------
__global__ void __launch_bounds__(256) k_scatter(
    const int* __restrict__ src, const int* __restrict__ dst,
    const float* __restrict__ val, float* __restrict__ agg,
    float* __restrict__ cnt, int E, int addCnt) {
  long long t = (long long)blockIdx.x * 256 + threadIdx.x;
  int e = (int)(t >> 4);
  int c = (int)(t & 15);
  if (e >= E) return;
  int s = src[e];
  int d = dst[e];
  atomicAdd(&agg[(size_t)d * H + c], val[(size_t)s * H + c]);
  if (addCnt && c == 0) atomicAdd(&cnt[d], 1.0f);
}

// ---------------------------------------------------------------------------
// combine1: h1 = relu(agg/max(cnt,1) + b1 + y1r); z2l = h1@W2l; z2r = h1@W2r
// ---------------------------------------------------------------------------
__global__ void __launch_bounds__(256) k_combine1(
    const float* __restrict__ agg, const float* __restrict__ cnt,
    const float* __restrict__ y1r, const float* __restrict__ b1,
    const float* __restrict__ W2l, const float* __restrict__ W2r,
    float* __restrict__ z2l, float* __restrict__ z2r) {
  int n = blockIdx.x * 256 + threadIdx.x;
  if (n >= N_NODES) return;
  float inv = 1.f / fmaxf(cnt[n], 1.f);
  const float4* ag = (const float4*)(agg + (size_t)n * H);
  const float4* yr = (const float4*)(y1r + (size_t)n * H);
  float h1[H];
#pragma unroll
  for (int q = 0; q < 4; ++q) {
    float4 a = ag[q];
    float4 y = yr[q];
    h1[4 * q + 0] = fmaxf(fmaf(a.x, inv, b1[4 * q + 0] + y.x), 0.f);
    h1[4 * q + 1] = fmaxf(fmaf(a.y, inv, b1[4 * q + 1] + y.y), 0.f);
    h1[4 * q + 2] = fmaxf(fmaf(a.z, inv, b1[4 * q + 2] + y.z), 0.f);
    h1[4 * q + 3] = fmaxf(fmaf(a.w, inv, b1[4 * q + 3] + y.w), 0.f);
  }
  float zl[H], zr[H];
#pragma unroll
  for (int c = 0; c < H; ++c) { zl[c] = 0.f; zr[c] = 0.f; }
  for (int k = 0; k < H; ++k) {
    float hk = h1[k];
#pragma unroll
    for (int c = 0; c < H; ++c) {
      zl[c] = fmaf(hk, W2l[k * H + c], zl[c]);
      zr[c] = fmaf(hk, W2r[k * H + c], zr[c]);
    }
  }
  float4* outl = (float4*)(z2l + (size_t)n * H);
  float4* outr = (float4*)(z2r + (size_t)n * H);
#pragma unroll
  for (int q = 0; q < 4; ++q) {
    outl[q] = make_float4(zl[4 * q], zl[4 * q + 1], zl[4 * q + 2], zl[4 * q + 3]);
    outr[q] = make_float4(zr[4 * q], zr[4 * q + 1], zr[4 * q + 2], zr[4 * q + 3]);
  }
}

// ---------------------------------------------------------------------------
// combine2: h2 = agg2/max(cnt,1) + b2 + z2r
// ---------------------------------------------------------------------------
__global__ void __launch_bounds__(256) k_combine2(
    const float* __restrict__ agg2, const float* __restrict__ cnt,
    const float* __restrict__ z2r, const float* __restrict__ b2,
    float* __restrict__ h2) {
  int n = blockIdx.x * 256 + threadIdx.x;
  if (n >= N_NODES) return;
  float inv = 1.f / fmaxf(cnt[n], 1.f);
  const float4* ag = (const float4*)(agg2 + (size_t)n * H);
  const float4* zr = (const float4*)(z2r + (size_t)n * H);
  float4* out = (float4*)(h2 + (size_t)n * H);
#pragma unroll
  for (int q = 0; q < 4; ++q) {
    float4 a = ag[q];
    float4 z = zr[q];
    float4 o;
    o.x = fmaf(a.x, inv, b2[4 * q + 0] + z.x);
    o.y = fmaf(a.y, inv, b2[4 * q + 1] + z.y);
    o.z = fmaf(a.z, inv, b2[4 * q + 2] + z.z);
    o.w = fmaf(a.w, inv, b2[4 * q + 3] + z.w);
    out[q] = o;
  }
}

// ---------------------------------------------------------------------------
// decode: out[p] = sigmoid(dot(h2[s], h2[d]))
// ---------------------------------------------------------------------------
__global__ void __launch_bounds__(256) k_decode(
    const int* __restrict__ ps, const int* __restrict__ pd,
    const float* __restrict__ h2, float* __restrict__ out, int P) {
  int p = blockIdx.x * 256 + threadIdx.x;
  if (p >= P) return;
  int a = ps[p];
  int b = pd[p];
  const float4* ha = (const float4*)(h2 + (size_t)a * H);
  const float4* hb = (const float4*)(h2 + (size_t)b * H);
  float acc = 0.f;
#pragma unroll
  for (int q = 0; q < 4; ++q) {
    float4 u = ha[q];
    float4 v = hb[q];
    acc = fmaf(u.x, v.x, acc);
    acc = fmaf(u.y, v.y, acc);
    acc = fmaf(u.z, v.z, acc);
    acc = fmaf(u.w, v.w, acc);
  }
  out[p] = 1.f / (1.f + __expf(-acc));
}

// ---------------------------------------------------------------------------
extern "C" void kernel_launch(void* const* d_in, const int* in_sizes, int n_in,
                              void* d_out, int out_size, void* d_ws, size_t ws_size,
                              hipStream_t stream) {
  const float* x   = (const float*)d_in[0];
  const float* W1l = (const float*)d_in[1];
  const float* b1  = (const float*)d_in[2];
  const float* W1r = (const float*)d_in[3];
  const float* W2l = (const float*)d_in[4];
  const float* b2  = (const float*)d_in[5];
  const float* W2r = (const float*)d_in[6];
  const int* ei = (const int*)d_in[7];  // [2, E] int32
  const int* di = (const int*)d_in[8];  // [2, P] int32
  const int E = in_sizes[7] / 2;
  const int P = in_sizes[8] / 2;

  const size_t NF = (size_t)N_NODES * H;
  float* A    = (float*)d_ws;   // y1l, later agg2
  float* B    = A + NF;         // y1r, later h2
  float* C    = B + NF;         // agg1
  float* D    = C + NF;         // z2l
  float* Ez   = D + NF;         // z2r
  float* cnt  = Ez + NF;        // [N] degree (float)

  const int nodeBlocks = (N_NODES + 255) / 256;
  const long long scatterThreads = (long long)E * 16;
  const int scatterBlocks = (int)((scatterThreads + 255) / 256);

  // layer 1 projection
  k_lin1<<<nodeBlocks, 256, 0, stream>>>(x, W1l, W1r, A, B);
  // aggregate pass 1 (+ degree)
  hipMemsetAsync(C, 0, NF * sizeof(float), stream);
  hipMemsetAsync(cnt, 0, N_NODES * sizeof(float), stream);
  k_scatter<<<scatterBlocks, 256, 0, stream>>>(ei, ei + E, A, C, cnt, E, 1);
  // combine layer 1 + project layer 2
  k_combine1<<<nodeBlocks, 256, 0, stream>>>(C, cnt, B, b1, W2l, W2r, D, Ez);
  // aggregate pass 2 (reuse cnt)
  hipMemsetAsync(A, 0, NF * sizeof(float), stream);
  k_scatter<<<scatterBlocks, 256, 0, stream>>>(ei, ei + E, D, A, cnt, E, 0);
  // combine layer 2 -> h2 (into B)
  k_combine2<<<nodeBlocks, 256, 0, stream>>>(A, cnt, Ez, b2, B);
  // decode
  k_decode<<<(P + 255) / 256, 256, 0, stream>>>(di, di + P, B, (float*)d_out, P);
}

// Round 2
// 400.277 us; speedup vs baseline: 1.1391x; 1.1391x over previous
//
#include <hip/hip_runtime.h>

#define N_NODES 100000
#define F_IN 128
#define H 16
#define CHUNK 256          // scan chunk size
#define NCHUNK ((N_NODES + CHUNK - 1) / CHUNK)   // 391

// ---------------------------------------------------------------------------
// k_lin1: y1l = x @ W1l, y1r = x @ W1r  (thread per node)
// ---------------------------------------------------------------------------
__global__ void __launch_bounds__(256) k_lin1(
    const float* __restrict__ x, const float* __restrict__ W1l,
    const float* __restrict__ W1r, float* __restrict__ y1l,
    float* __restrict__ y1r) {
  int n = blockIdx.x * 256 + threadIdx.x;
  if (n >= N_NODES) return;
  const float4* xr = (const float4*)(x + (size_t)n * F_IN);
  float al[H], ar[H];
#pragma unroll
  for (int c = 0; c < H; ++c) { al[c] = 0.f; ar[c] = 0.f; }
  float4 xv = xr[0];
  for (int k4 = 0; k4 < F_IN / 4; ++k4) {
    float4 cur = xv;
    if (k4 + 1 < F_IN / 4) xv = xr[k4 + 1];  // prefetch next 16B
    float xs[4] = {cur.x, cur.y, cur.z, cur.w};
#pragma unroll
    for (int j = 0; j < 4; ++j) {
      int k = k4 * 4 + j;
#pragma unroll
      for (int c = 0; c < H; ++c) {
        al[c] = fmaf(xs[j], W1l[k * H + c], al[c]);
        ar[c] = fmaf(xs[j], W1r[k * H + c], ar[c]);
      }
    }
  }
  float4* ol = (float4*)(y1l + (size_t)n * H);
  float4* orr = (float4*)(y1r + (size_t)n * H);
#pragma unroll
  for (int q = 0; q < 4; ++q) {
    ol[q] = make_float4(al[4 * q], al[4 * q + 1], al[4 * q + 2], al[4 * q + 3]);
    orr[q] = make_float4(ar[4 * q], ar[4 * q + 1], ar[4 * q + 2], ar[4 * q + 3]);
  }
}

// ---------------------------------------------------------------------------
// CSR build: degree histogram
// ---------------------------------------------------------------------------
__global__ void __launch_bounds__(256) k_deg(
    const int* __restrict__ dst, int* __restrict__ deg, int E) {
  int e = blockIdx.x * 256 + threadIdx.x;
  if (e >= E) return;
  atomicAdd(&deg[dst[e]], 1);
}

// scan pass 1: per-chunk exclusive scan + chunk totals
__global__ void __launch_bounds__(CHUNK) k_scan1(
    const int* __restrict__ deg, int* __restrict__ offl,
    int* __restrict__ blockSums, int n) {
  __shared__ int s[CHUNK];
  int t = threadIdx.x;
  int g = blockIdx.x * CHUNK + t;
  int v = (g < n) ? deg[g] : 0;
  s[t] = v;
  __syncthreads();
  for (int o = 1; o < CHUNK; o <<= 1) {
    int u = (t >= o) ? s[t - o] : 0;
    __syncthreads();
    s[t] += u;
    __syncthreads();
  }
  if (g < n) offl[g] = s[t] - v;           // exclusive within chunk
  if (t == CHUNK - 1) blockSums[blockIdx.x] = s[t];
}

// scan pass 2: exclusive scan of chunk totals (NCHUNK=391 <= 512)
__global__ void __launch_bounds__(512) k_scan2(
    const int* __restrict__ blockSums, int* __restrict__ bbase, int n) {
  __shared__ int s[512];
  int t = threadIdx.x;
  int v = (t < n) ? blockSums[t] : 0;
  s[t] = v;
  __syncthreads();
  for (int o = 1; o < 512; o <<= 1) {
    int u = (t >= o) ? s[t - o] : 0;
    __syncthreads();
    s[t] += u;
    __syncthreads();
  }
  if (t < n) bbase[t] = s[t] - v;
}

// bucket fill: srcSorted[CSR slot] = src[e]
__global__ void __launch_bounds__(256) k_fill(
    const int* __restrict__ src, const int* __restrict__ dst,
    const int* __restrict__ offl, const int* __restrict__ bbase,
    int* __restrict__ cur, int* __restrict__ srcSorted, int E) {
  int e = blockIdx.x * 256 + threadIdx.x;
  if (e >= E) return;
  int d = dst[e];
  int p = atomicAdd(&cur[d], 1);
  srcSorted[offl[d] + bbase[d >> 8] + p] = src[e];
}

// ---------------------------------------------------------------------------
// gather1 (fused combine1): h1 = relu(mean(y1l_nbrs) + b1 + y1r);
//                           z2l = h1@W2l; z2r = h1@W2r
// 16 lanes per node, lane c owns channel c. W2 GEMM via 16-wide shuffles.
// ---------------------------------------------------------------------------
__global__ void __launch_bounds__(256) k_gather1(
    const int* __restrict__ srcSorted, const int* __restrict__ deg,
    const int* __restrict__ offl, const int* __restrict__ bbase,
    const float* __restrict__ y1l, const float* __restrict__ y1r,
    const float* __restrict__ b1, const float* __restrict__ W2l,
    const float* __restrict__ W2r, float* __restrict__ z2l,
    float* __restrict__ z2r) {
  int tid = blockIdx.x * 256 + threadIdx.x;
  int n = tid >> 4;
  int c = tid & 15;
  if (n >= N_NODES) return;
  int beg = offl[n] + bbase[n >> 8];
  int dg = deg[n];
  int end = beg + dg;
  float acc = 0.f;
  int i = beg;
  for (; i + 4 <= end; i += 4) {  // 4-deep for memory-level parallelism
    int s0 = srcSorted[i], s1 = srcSorted[i + 1];
    int s2 = srcSorted[i + 2], s3 = srcSorted[i + 3];
    float a0 = y1l[(size_t)s0 * H + c];
    float a1 = y1l[(size_t)s1 * H + c];
    float a2 = y1l[(size_t)s2 * H + c];
    float a3 = y1l[(size_t)s3 * H + c];
    acc += (a0 + a1) + (a2 + a3);
  }
  for (; i < end; ++i) acc += y1l[(size_t)srcSorted[i] * H + c];
  float inv = 1.f / fmaxf((float)dg, 1.f);
  float h1 = fmaxf(fmaf(acc, inv, b1[c] + y1r[(size_t)n * H + c]), 0.f);
  float zl = 0.f, zr = 0.f;
#pragma unroll
  for (int k = 0; k < H; ++k) {
    float hk = __shfl(h1, k, 16);
    zl = fmaf(hk, W2l[k * H + c], zl);
    zr = fmaf(hk, W2r[k * H + c], zr);
  }
  z2l[(size_t)n * H + c] = zl;
  z2r[(size_t)n * H + c] = zr;
}

// ---------------------------------------------------------------------------
// gather2 (fused combine2): h2 = mean(z2l_nbrs) + b2 + z2r
// ---------------------------------------------------------------------------
__global__ void __launch_bounds__(256) k_gather2(
    const int* __restrict__ srcSorted, const int* __restrict__ deg,
    const int* __restrict__ offl, const int* __restrict__ bbase,
    const float* __restrict__ z2l, const float* __restrict__ z2r,
    const float* __restrict__ b2, float* __restrict__ h2) {
  int tid = blockIdx.x * 256 + threadIdx.x;
  int n = tid >> 4;
  int c = tid & 15;
  if (n >= N_NODES) return;
  int beg = offl[n] + bbase[n >> 8];
  int dg = deg[n];
  int end = beg + dg;
  float acc = 0.f;
  int i = beg;
  for (; i + 4 <= end; i += 4) {
    int s0 = srcSorted[i], s1 = srcSorted[i + 1];
    int s2 = srcSorted[i + 2], s3 = srcSorted[i + 3];
    float a0 = z2l[(size_t)s0 * H + c];
    float a1 = z2l[(size_t)s1 * H + c];
    float a2 = z2l[(size_t)s2 * H + c];
    float a3 = z2l[(size_t)s3 * H + c];
    acc += (a0 + a1) + (a2 + a3);
  }
  for (; i < end; ++i) acc += z2l[(size_t)srcSorted[i] * H + c];
  float inv = 1.f / fmaxf((float)dg, 1.f);
  h2[(size_t)n * H + c] = fmaf(acc, inv, b2[c] + z2r[(size_t)n * H + c]);
}

// ---------------------------------------------------------------------------
// decode: out[p] = sigmoid(dot(h2[s], h2[d]))
// ---------------------------------------------------------------------------
__global__ void __launch_bounds__(256) k_decode(
    const int* __restrict__ ps, const int* __restrict__ pd,
    const float* __restrict__ h2, float* __restrict__ out, int P) {
  int p = blockIdx.x * 256 + threadIdx.x;
  if (p >= P) return;
  int a = ps[p];
  int b = pd[p];
  const float4* ha = (const float4*)(h2 + (size_t)a * H);
  const float4* hb = (const float4*)(h2 + (size_t)b * H);
  float acc = 0.f;
#pragma unroll
  for (int q = 0; q < 4; ++q) {
    float4 u = ha[q];
    float4 v = hb[q];
    acc = fmaf(u.x, v.x, acc);
    acc = fmaf(u.y, v.y, acc);
    acc = fmaf(u.z, v.z, acc);
    acc = fmaf(u.w, v.w, acc);
  }
  out[p] = 1.f / (1.f + __expf(-acc));
}

// ---------------------------------------------------------------------------
extern "C" void kernel_launch(void* const* d_in, const int* in_sizes, int n_in,
                              void* d_out, int out_size, void* d_ws, size_t ws_size,
                              hipStream_t stream) {
  const float* x   = (const float*)d_in[0];
  const float* W1l = (const float*)d_in[1];
  const float* b1  = (const float*)d_in[2];
  const float* W1r = (const float*)d_in[3];
  const float* W2l = (const float*)d_in[4];
  const float* b2  = (const float*)d_in[5];
  const float* W2r = (const float*)d_in[6];
  const int* ei = (const int*)d_in[7];  // [2, E] int32
  const int* di = (const int*)d_in[8];  // [2, P] int32
  const int E = in_sizes[7] / 2;
  const int P = in_sizes[8] / 2;

  const size_t NF = (size_t)N_NODES * H;
  // float buffers (aliasing: z2r <- y1r is safe, gather1 reads y1r[n] only
  // for its own row before writing z2r[n]; h2 <- y1l is safe, y1l dead
  // after gather1 and gather2 doesn't read it)
  float* y1l = (float*)d_ws;        // NF; later aliased as h2
  float* y1r = y1l + NF;            // NF; later aliased as z2r
  float* z2l = y1r + NF;            // NF
  float* z2r = y1r;                 // alias
  float* h2  = y1l;                 // alias
  // int buffers
  int* srcSorted = (int*)(z2l + NF);        // E
  int* deg  = srcSorted + E;                // N
  int* offl = deg + N_NODES;                // N
  int* bbase = offl + N_NODES;              // 512 (NCHUNK=391 padded)
  int* cur  = bbase + 512;                  // N
  int* blockSums = cur + N_NODES;           // NCHUNK

  const int nodeBlocks = (N_NODES + 255) / 256;
  const int edgeBlocks = (E + 255) / 256;
  const int gatherBlocks = ((N_NODES * H) + 255) / 256;

  // zero counters
  hipMemsetAsync(deg, 0, N_NODES * sizeof(int), stream);
  hipMemsetAsync(cur, 0, N_NODES * sizeof(int), stream);

  // layer-1 projection (independent of CSR build)
  k_lin1<<<nodeBlocks, 256, 0, stream>>>(x, W1l, W1r, y1l, y1r);

  // CSR build
  k_deg<<<edgeBlocks, 256, 0, stream>>>(ei + E, deg, E);
  k_scan1<<<NCHUNK, CHUNK, 0, stream>>>(deg, offl, blockSums, N_NODES);
  k_scan2<<<1, 512, 0, stream>>>(blockSums, bbase, NCHUNK);
  k_fill<<<edgeBlocks, 256, 0, stream>>>(ei, ei + E, offl, bbase, cur,
                                         srcSorted, E);

  // layer 1 aggregate + combine + layer-2 projection
  k_gather1<<<gatherBlocks, 256, 0, stream>>>(srcSorted, deg, offl, bbase,
                                              y1l, y1r, b1, W2l, W2r,
                                              z2l, z2r);
  // layer 2 aggregate + combine
  k_gather2<<<gatherBlocks, 256, 0, stream>>>(srcSorted, deg, offl, bbase,
                                              z2l, z2r, b2, h2);
  // decode
  k_decode<<<(P + 255) / 256, 256, 0, stream>>>(di, di + P, h2, (float*)d_out, P);
}